// Round 4
// baseline (647.760 us; speedup 1.0000x reference)
//
#include <hip/hip_runtime.h>
#include <math.h>

#define N_DIM 1000
#define P_DIM 50000
#define Z_DIM 10
#define L_DIM 5
#define NT 256
#define NB 196          // ceil(50000/256); persistent grid (<=256 CUs, co-resident)
#define NW (NB * 4)     // 784 waves total
#define NSPLIT 4
#define NCHUNK 250      // N_DIM / NSPLIT
#define NSTEPS 50       // Z_DIM * L_DIM
#define NSLOT 13        // ceil(NW / 64) partials polled per lane
#define NEG_BIG (-3.0e38f)

// ---- workspace layout (floats) ----
constexpr size_t ZP       = (size_t)Z_DIM * P_DIM;     // 500000
constexpr size_t OFF_ZTR  = 0;                         // [Z][P]
constexpr size_t OFF_W    = ZP;                        // [Z][P]
constexpr size_t OFF_ZZ   = 2 * ZP;                    // [Z*Z], reserve 128
constexpr size_t OFF_PART = 2 * ZP + 128;              // NSTEPS x NW x u64 (8B aligned)
constexpr size_t WS_ZERO  = OFF_PART + (size_t)NSTEPS * NW * 2;  // floats to zero

// ---- output layout (floats) ----
constexpr size_t OUT_VW = (size_t)L_DIM * Z_DIM * P_DIM;          // 2,500,000
constexpr size_t OUT_AL = OUT_VW + (size_t)L_DIM * Z_DIM;         // 2,500,050

__device__ inline unsigned long long pack2(float m, float e) {
    return (unsigned long long)__float_as_uint(m) |
           ((unsigned long long)__float_as_uint(e) << 32);
}

// Online-softmax merge. NEG_BIG (not -INF) avoids NaN from inf-inf.
__device__ inline void online_merge(float& m, float& e, float m2, float e2) {
    float M = fmaxf(m, m2);
    e = e * __expf(m - M) + e2 * __expf(m2 - M);
    m = M;
}

// Wave-level butterfly: all 64 lanes exit with merged (m,e). No LDS, no barriers.
__device__ inline void wave_merge(float& m, float& e) {
    #pragma unroll
    for (int off = 32; off > 0; off >>= 1) {
        float m2 = __shfl_xor(m, off);
        float e2 = __shfl_xor(e, off);
        online_merge(m, e, m2, e2);
    }
}

// mean_zz[i][j] = sum_n mean_z[n,i]*mean_z[n,j] + N*var_z[i,j]
__global__ __launch_bounds__(256) void init_zz(const float* __restrict__ mean_z,
                                               const float* __restrict__ var_z,
                                               float* __restrict__ ws) {
    float* zz = ws + OFF_ZZ;
    int i = blockIdx.x / Z_DIM, j = blockIdx.x % Z_DIM;
    float s = 0.f;
    for (int n = threadIdx.x; n < N_DIM; n += 256)
        s += mean_z[n * Z_DIM + i] * mean_z[n * Z_DIM + j];
    #pragma unroll
    for (int off = 32; off > 0; off >>= 1) s += __shfl_xor(s, off);
    __shared__ float ls[4];
    if ((threadIdx.x & 63) == 0) ls[threadIdx.x >> 6] = s;
    __syncthreads();
    if (threadIdx.x == 0) {
        float t = ls[0] + ls[1] + ls[2] + ls[3];
        zz[blockIdx.x] = t + (float)N_DIM * var_z[blockIdx.x];
    }
}

// ZtR[z][p] += chunk-sum of mean_z[n,z]*data[n,p]  (atomic, 4 n-chunks)
// W0[z][p]  = sum_l mean_w[l,z,p]*alpha[l,z,p]     (y==0 only)
__global__ __launch_bounds__(NT) void precompute_big(const float* __restrict__ data,
                                                     const float* __restrict__ mean_z,
                                                     const float* __restrict__ mw0,
                                                     const float* __restrict__ al0,
                                                     float* __restrict__ ws) {
    float* ZtR = ws + OFF_ZTR;
    float* W   = ws + OFF_W;
    __shared__ float mzs[NCHUNK * Z_DIM];   // 10 KB
    int n0 = blockIdx.y * NCHUNK;
    for (int i = threadIdx.x; i < NCHUNK * Z_DIM; i += NT)
        mzs[i] = mean_z[n0 * Z_DIM + i];
    __syncthreads();
    int p = blockIdx.x * NT + threadIdx.x;
    if (p >= P_DIM) return;

    float acc[Z_DIM];
    #pragma unroll
    for (int z = 0; z < Z_DIM; z++) acc[z] = 0.f;
    for (int r = 0; r < NCHUNK; r++) {
        float d = data[(size_t)(n0 + r) * P_DIM + p];
        #pragma unroll
        for (int z = 0; z < Z_DIM; z++) acc[z] += mzs[r * Z_DIM + z] * d;
    }
    #pragma unroll
    for (int z = 0; z < Z_DIM; z++) atomicAdd(&ZtR[(size_t)z * P_DIM + p], acc[z]);

    if (blockIdx.y == 0) {
        #pragma unroll
        for (int z = 0; z < Z_DIM; z++) {
            float w = 0.f;
            #pragma unroll
            for (int l = 0; l < L_DIM; l++) {
                size_t io = ((size_t)l * Z_DIM + z) * P_DIM + p;
                w += mw0[io] * al0[io];
            }
            W[(size_t)z * P_DIM + p] = w;
        }
    }
}

// Persistent kernel: 50 sequential (k,l) steps. The per-wave (m,e) u64 partial
// IS the barrier signal (e-field+1 nonzero sentinel, per-step buffers, no
// counter, no fences, no __syncthreads anywhere in the loop).
__global__ __launch_bounds__(NT) void fused_steps(const float* __restrict__ mw0,
                                                  const float* __restrict__ al0,
                                                  const float* __restrict__ pi,
                                                  const float* __restrict__ tau0,
                                                  const float* __restrict__ taup,
                                                  float* __restrict__ ws,
                                                  float* __restrict__ out) {
    float* ZtR = ws + OFF_ZTR;
    float* Wg  = ws + OFF_W;
    float* zz  = ws + OFF_ZZ;
    unsigned long long* part = (unsigned long long*)(ws + OFF_PART);

    float* out_mw = out;
    float* out_vw = out + OUT_VW;
    float* out_al = out + OUT_AL;

    int tid  = threadIdx.x;
    int blk  = blockIdx.x;
    int lane = tid & 63;
    int wav  = blk * 4 + (tid >> 6);        // global wave id, 0..NW-1
    int p = blk * NT + tid;
    bool valid = p < P_DIM;
    float tau = taup[0];

    float W[Z_DIM];
    #pragma unroll
    for (int z = 0; z < Z_DIM; z++)
        W[z] = valid ? Wg[(size_t)z * P_DIM + p] : 0.f;

    // prefetched operands for the *current* step
    float nx_mw = 0.f, nx_al = 0.f, nx_ztr = 0.f, nx_pi = 1.f;
    if (valid) {
        nx_mw  = mw0[p];
        nx_al  = al0[p];
        nx_ztr = ZtR[p];
        nx_pi  = pi[p];
    }

    float wk = 0.f, r = 0.f, lp = 0.f;
    int k = 0, l = 0;
    for (int s = 0; s < NSTEPS; s++) {
        // uniform per-step scalars (tiny, L2-hot)
        float Ezz   = zz[k * Z_DIM + k];
        float t0v   = tau0[l * Z_DIM + k];
        float u_var = 1.f / (tau * Ezz + t0v);
        float s2    = 1.f / (Ezz * tau);
        float s0inv = 1.f / t0v;
        float cq    = 0.5f * (tau / Ezz) * (s0inv / (s2 + s0inv));

        if (l == 0) {
            r = nx_ztr;
            #pragma unroll
            for (int j = 0; j < Z_DIM; j++)
                if (j != k) r -= zz[k * Z_DIM + j] * W[j];
            wk = W[k];
            lp = __logf(nx_pi);
        }

        size_t io = ((size_t)l * Z_DIM + k) * P_DIM + p;
        float wkl = wk - nx_mw * nx_al;
        float E   = r - Ezz * wkl;
        float um  = tau * u_var * E;
        float lgt = valid ? (lp + cq * E * E) : NEG_BIG;

        // wave-local online-softmax reduce (registers only)
        float m = lgt, e = valid ? 1.f : 0.f;
        wave_merge(m, e);

        // signal: single u64 atomic store — data is its own flag (e+1 != 0)
        unsigned long long* pbuf = part + (size_t)s * NW;
        if (lane == 0)
            __hip_atomic_store(&pbuf[wav], pack2(m, e + 1.0f),
                               __ATOMIC_RELAXED, __HIP_MEMORY_SCOPE_AGENT);

        // work issued after the signal hides under the poll:
        if (valid) out_mw[io] = um;
        if (blk == 0 && tid == 0) out_vw[l * Z_DIM + k] = u_var;

        int l2 = l + 1, k2 = k;
        if (l2 == L_DIM) { l2 = 0; k2++; }
        if (s + 1 < NSTEPS && valid) {
            size_t io2 = ((size_t)l2 * Z_DIM + k2) * P_DIM + p;
            nx_mw = mw0[io2];
            nx_al = al0[io2];
            if (l2 == 0) {
                nx_ztr = ZtR[(size_t)k2 * P_DIM + p];
                nx_pi  = pi[(size_t)k2 * P_DIM + p];
            }
        }

        // poll all NW partials (12-13 per lane, pipelined issue + retry mask)
        unsigned long long vv[NSLOT];
        unsigned pend = 0;
        #pragma unroll
        for (int t = 0; t < NSLOT; t++) {
            int j = lane + t * 64;
            if (j < NW) {
                vv[t] = __hip_atomic_load(&pbuf[j], __ATOMIC_RELAXED,
                                          __HIP_MEMORY_SCOPE_AGENT);
                if ((unsigned)(vv[t] >> 32) == 0u) pend |= (1u << t);
            }
        }
        while (pend) {
            __builtin_amdgcn_s_sleep(1);
            #pragma unroll
            for (int t = 0; t < NSLOT; t++) {
                if (pend & (1u << t)) {
                    int j = lane + t * 64;
                    vv[t] = __hip_atomic_load(&pbuf[j], __ATOMIC_RELAXED,
                                              __HIP_MEMORY_SCOPE_AGENT);
                    if ((unsigned)(vv[t] >> 32) != 0u) pend &= ~(1u << t);
                }
            }
        }
        float mm = NEG_BIG, ee = 0.f;
        #pragma unroll
        for (int t = 0; t < NSLOT; t++) {
            int j = lane + t * 64;
            if (j < NW) {
                float m2 = __uint_as_float((unsigned)vv[t]);
                float e2 = __uint_as_float((unsigned)(vv[t] >> 32)) - 1.0f;
                online_merge(mm, ee, m2, e2);
            }
        }
        wave_merge(mm, ee);

        if (valid) {
            float a = __expf(lgt - mm) / ee;
            out_al[io] = a;
            wk = wkl + um * a;
            if (l == L_DIM - 1) W[k] = wk;   // register-only W update
        }
        l = l2; k = k2;
    }
}

extern "C" void kernel_launch(void* const* d_in, const int* in_sizes, int n_in,
                              void* d_out, int out_size, void* d_ws, size_t ws_size,
                              hipStream_t stream) {
    (void)in_sizes; (void)n_in; (void)out_size; (void)ws_size;
    const float* data   = (const float*)d_in[0];
    const float* mean_z = (const float*)d_in[1];
    const float* var_z  = (const float*)d_in[2];
    const float* mw0    = (const float*)d_in[3];
    // d_in[4] var_w: unused (fully overwritten in output)
    const float* al0    = (const float*)d_in[5];
    const float* tau0   = (const float*)d_in[6];
    const float* pi     = (const float*)d_in[7];
    const float* taup   = (const float*)d_in[8];
    float* out = (float*)d_out;
    float* ws  = (float*)d_ws;

    // single memset: ZtR accumulator + (W, zz scratch) + all partial buffers
    hipMemsetAsync(ws, 0, WS_ZERO * sizeof(float), stream);

    init_zz<<<Z_DIM * Z_DIM, 256, 0, stream>>>(mean_z, var_z, ws);
    precompute_big<<<dim3(NB, NSPLIT), NT, 0, stream>>>(data, mean_z, mw0, al0, ws);
    fused_steps<<<NB, NT, 0, stream>>>(mw0, al0, pi, tau0, taup, ws, out);
}